// Round 9
// baseline (47.706 us; speedup 1.0000x reference)
//
#include <hip/hip_runtime.h>

#define M_HALF 16384
#define D 128
#define C 64

#define K1_BLOCKS 256
#define K1_ROWS 64
#define LDX 132                         // xs leading dim (floats), rows 16B-aligned

#define K2_BLOCKS 256

#define K3_BLOCKS 256
#define K3_ROWS 64
#define LDX4 33                         // xrows4 float4 leading dim

// ---- K1: ballot-gather prototype partials; block 0 also: y histogram ------
__global__ __launch_bounds__(256) void k1_partials(
    const float* __restrict__ x, const int* __restrict__ y,
    float* __restrict__ partials,   // [K1_BLOCKS][C*D]  c-major: [c][k]
    float* __restrict__ cntSum)     // [C] written by block 0 only (plain stores)
{
    __shared__ float xs[K1_ROWS * LDX];      // 33.8 KB
    __shared__ int   hist[C];
    const int tid  = threadIdx.x;
    const int lane = tid & 63;
    const int kq   = tid >> 6;               // wave id = k-quarter
    const int base = blockIdx.x * K1_ROWS;

    // stage 64 rows, coalesced float4
    const float4* x4 = (const float4*)(x + (size_t)base * D);
    #pragma unroll
    for (int it = 0; it < 8; ++it) {
        const int i = it * 256 + tid;        // 0..2047
        const int row = i >> 5, k4 = i & 31;
        *(float4*)&xs[row * LDX + k4 * 4] = x4[i];
    }

    // per-wave: build 64-bit row mask for class == lane
    const int ycl = y[base + lane];          // class of row 'lane'
    unsigned long long mymask = 0ULL;
    for (int ci = 0; ci < C; ++ci) {
        const unsigned long long m = __ballot(ycl == ci);
        if (lane == ci) mymask = m;
    }
    __syncthreads();                         // xs ready

    // gather-accumulate into registers: class=lane, k in [kq*32, kq*32+32)
    float acc[32];
    #pragma unroll
    for (int j = 0; j < 32; ++j) acc[j] = 0.f;
    unsigned long long m = mymask;
    while (m) {
        const int r = (int)__builtin_ctzll(m);
        m &= m - 1;
        const float* xr = &xs[r * LDX + kq * 32];
        #pragma unroll
        for (int j = 0; j < 32; ++j) acc[j] += xr[j];
    }

    // plain stores: partials[blk][lane*D + kq*32 + j]
    float* outp = partials + (size_t)blockIdx.x * (C * D) + lane * D + kq * 32;
    #pragma unroll
    for (int j4 = 0; j4 < 8; ++j4)
        *(float4*)&outp[j4 * 4] =
            make_float4(acc[j4*4], acc[j4*4+1], acc[j4*4+2], acc[j4*4+3]);

    // block 0: exact class histogram of the support half (native int LDS atomics)
    if (blockIdx.x == 0) {
        if (tid < C) hist[tid] = 0;
        __syncthreads();
        #pragma unroll 8
        for (int it = 0; it < M_HALF / 256; ++it)
            atomicAdd(&hist[y[it * 256 + tid]], 1);
        __syncthreads();
        if (tid < C) cntSum[tid] = (float)hist[tid];
    }
}

// ---- K2: wide partial reduction -> finalized pT table in K3 layout --------
// 8192 (c,k) pairs; 256 blocks x 32 pairs; 8 threads/pair sum 32 partials.
__global__ __launch_bounds__(256) void k2_finalize(
    const float* __restrict__ partials, const float* __restrict__ cntSum,
    float* __restrict__ pTg,    // float idx: (k4*64 + cc*16 + cg)*4 + j
    float* __restrict__ out)
{
    __shared__ float red[8][33];
    const int tid  = threadIdx.x;
    const int sub  = tid >> 5;              // 0..7
    const int pidx = tid & 31;              // 0..31
    const int q    = blockIdx.x * 32 + pidx;    // flat (c,k): c=q>>7, k=q&127

    if (blockIdx.x == 0 && tid == 64) out[0] = 0.f;   // zero loss accumulator

    float s = 0.f;
    const int b0 = sub * 32;
    #pragma unroll 8
    for (int i = 0; i < 32; ++i)
        s += partials[(size_t)(b0 + i) * (C * D) + q];   // 128B coalesced
    red[sub][pidx] = s;
    __syncthreads();

    if (tid < 32) {
        float tot = 0.f;
        #pragma unroll
        for (int u = 0; u < 8; ++u) tot += red[u][tid];
        const int qq = blockIdx.x * 32 + tid;
        const int c = qq >> 7, k = qq & 127;
        float cnt = cntSum[c];
        if (cnt < 0.5f) cnt = 1.f;          // class_counts + (counts < 0.01)
        tot /= cnt;
        pTg[((k >> 2) * 64 + (c & 3) * 16 + (c >> 2)) * 4 + (k & 3)] = tot;
    }
}

// ---- K3: 4x4-register-tile distances + logsumexp + atomic loss ------------
__global__ __launch_bounds__(256, 2) void k3_dist_loss(
    const float* __restrict__ x, const int* __restrict__ y,
    const float4* __restrict__ pTg4,    // [32][64] float4, finalized
    float* __restrict__ out)
{
    __shared__ float4 xrows4[K3_ROWS * LDX4];  // 33.8 KB, [row][k4] padded
    __shared__ float4 pT4[32 * 64];            // 32 KB, [k4][cc][cg]
    __shared__ float  wsum[4];
    const int tid = threadIdx.x;

    for (int o = tid; o < 32 * 64; o += 256) pT4[o] = pTg4[o];  // identity stage
    const int row0 = M_HALF + blockIdx.x * K3_ROWS;
    {
        const float4* src = (const float4*)(x + (size_t)row0 * D);
        for (int i = tid; i < K3_ROWS * (D / 4); i += 256)
            xrows4[(i >> 5) * LDX4 + (i & 31)] = src[i];
    }
    __syncthreads();

    const int lane = tid & 63;
    const int wid  = tid >> 6;
    const int cg   = lane & 15;      // classes 4*cg + cc
    const int rg   = lane >> 4;      // row group within wave
    const int rbase = wid * 16 + rg * 4;   // wave: 16 rows; thread: 4 rows

    float acc[4][4];
    #pragma unroll
    for (int r = 0; r < 4; ++r)
        #pragma unroll
        for (int cc = 0; cc < 4; ++cc) acc[r][cc] = 0.f;

    #pragma unroll 2
    for (int k4 = 0; k4 < 32; ++k4) {
        float4 pv[4], xv[4];
        #pragma unroll
        for (int cc = 0; cc < 4; ++cc) pv[cc] = pT4[k4 * 64 + cc * 16 + cg];
        #pragma unroll
        for (int r = 0; r < 4; ++r) xv[r] = xrows4[(rbase + r) * LDX4 + k4];
        #pragma unroll
        for (int r = 0; r < 4; ++r) {
            #pragma unroll
            for (int cc = 0; cc < 4; ++cc) {
                float d;
                d = xv[r].x - pv[cc].x; acc[r][cc] = fmaf(d, fabsf(d), acc[r][cc]);
                d = xv[r].y - pv[cc].y; acc[r][cc] = fmaf(d, fabsf(d), acc[r][cc]);
                d = xv[r].z - pv[cc].z; acc[r][cc] = fmaf(d, fabsf(d), acc[r][cc]);
                d = xv[r].w - pv[cc].w; acc[r][cc] = fmaf(d, fabsf(d), acc[r][cc]);
            }
        }
    }

    const float ninv_d = -1.f / (float)D;
    float lsum = 0.f;
    #pragma unroll
    for (int r = 0; r < 4; ++r) {
        float dv0 = acc[r][0] * ninv_d, dv1 = acc[r][1] * ninv_d;
        float dv2 = acc[r][2] * ninv_d, dv3 = acc[r][3] * ninv_d;
        float mx = fmaxf(fmaxf(dv0, dv1), fmaxf(dv2, dv3));
        #pragma unroll
        for (int off = 8; off; off >>= 1) mx = fmaxf(mx, __shfl_xor(mx, off));
        float se = __expf(dv0 - mx) + __expf(dv1 - mx) +
                   __expf(dv2 - mx) + __expf(dv3 - mx);
        #pragma unroll
        for (int off = 8; off; off >>= 1) se += __shfl_xor(se, off);
        const float lse = mx + __logf(se);

        const int yt  = y[row0 + rbase + r];     // uniform within 16-lane group
        const int cct = yt & 3, cgt = yt >> 2;   // class c = 4*cg + cc
        const float v01 = (cct & 1) ? dv1 : dv0;
        const float v23 = (cct & 1) ? dv3 : dv2;
        const float val = (cct & 2) ? v23 : v01;
        const float dy  = __shfl(val, (lane & 48) | cgt);
        lsum += lse - dy;                        // -logp[y]
    }

    lsum += __shfl_xor(lsum, 16);                // sum 4 rg-groups
    lsum += __shfl_xor(lsum, 32);

    if (lane == 0) wsum[wid] = lsum;
    __syncthreads();
    if (tid == 0) {
        const float tot = (wsum[0] + wsum[1] + wsum[2] + wsum[3]) * (1.f / (float)M_HALF);
        atomicAdd(out, tot);
    }
}

extern "C" void kernel_launch(void* const* d_in, const int* in_sizes, int n_in,
                              void* d_out, int out_size, void* d_ws, size_t ws_size,
                              hipStream_t stream) {
    const float* x = (const float*)d_in[0];   // [32768][128]
    const int*   y = (const int*)d_in[1];     // [32768]
    float* out = (float*)d_out;

    float* ws_f     = (float*)d_ws;
    float* cntSum   = ws_f;                              // 64 floats
    float* pTg      = cntSum + C;                        // 8192 floats
    float* partials = pTg + D * C;                       // 256*8192 = 8 MB

    k1_partials<<<K1_BLOCKS, 256, 0, stream>>>(x, y, partials, cntSum);
    k2_finalize<<<K2_BLOCKS, 256, 0, stream>>>(partials, cntSum, pTg, out);
    k3_dist_loss<<<K3_BLOCKS, 256, 0, stream>>>(x, y, (const float4*)pTg, out);
}

// Round 10
// 43.593 us; speedup vs baseline: 1.0944x; 1.0944x over previous
//
#include <hip/hip_runtime.h>

#define M_HALF 16384
#define D 128
#define C 64

#define K1_BLOCKS 256
#define K1_ROWS 64

#define K2_BLOCKS 256

#define K3_BLOCKS 256
#define K3_ROWS 64
#define LDX4 33                         // xrows4 float4 leading dim

// ---- K1: ballot + direct-global gather; zero LDS; coalesced partials ------
__global__ __launch_bounds__(256) void k1_partials(
    const float* __restrict__ x, const int* __restrict__ y,
    float* __restrict__ partials,   // [K1_BLOCKS][4][C][32]  (kq, c, j)
    float* __restrict__ cntSum)     // [C] pre-zeroed; integer-valued atomics
{
    const int tid  = threadIdx.x;
    const int lane = tid & 63;
    const int kq   = tid >> 6;               // wave id = k-quarter
    const int base = blockIdx.x * K1_ROWS;

    // per-wave: 64-bit row mask for class == lane
    const int ycl = y[base + lane];          // class of row 'lane'
    unsigned long long mymask = 0ULL;
    for (int ci = 0; ci < C; ++ci) {
        const unsigned long long m = __ballot(ycl == ci);
        if (lane == ci) mymask = m;
    }
    if (kq == 0) {                           // counts: exact ints, deterministic
        const float cnt = (float)__popcll(mymask);
        if (cnt > 0.f) atomicAdd(&cntSum[lane], cnt);
    }

    // gather-accumulate from global: class=lane, k in [kq*32, kq*32+32)
    float acc[32];
    #pragma unroll
    for (int j = 0; j < 32; ++j) acc[j] = 0.f;
    unsigned long long m = mymask;
    while (m) {
        const int r = (int)__builtin_ctzll(m);
        m &= m - 1;
        const float4* xr = (const float4*)(x + (size_t)(base + r) * D + kq * 32);
        #pragma unroll
        for (int j4 = 0; j4 < 8; ++j4) {
            const float4 v = xr[j4];
            acc[j4*4+0] += v.x; acc[j4*4+1] += v.y;
            acc[j4*4+2] += v.z; acc[j4*4+3] += v.w;
        }
    }

    // coalesced store: per-lane 128B contiguous, per-wave 8KB contiguous
    float* outp = partials + (size_t)blockIdx.x * (C * D) + (kq * 64 + lane) * 32;
    #pragma unroll
    for (int j4 = 0; j4 < 8; ++j4)
        *(float4*)&outp[j4 * 4] =
            make_float4(acc[j4*4], acc[j4*4+1], acc[j4*4+2], acc[j4*4+3]);
}

// ---- K2: wide partial reduction -> finalized pT table in K3 layout --------
// 8192 flat slots q = kq*2048 + c*32 + j; 256 blocks x 32 slots; 8 thr/slot.
__global__ __launch_bounds__(256) void k2_finalize(
    const float* __restrict__ partials, const float* __restrict__ cntSum,
    float* __restrict__ pTg,    // float idx: (k4*64 + cc*16 + cg)*4 + j
    float* __restrict__ out)
{
    __shared__ float red[8][33];
    const int tid  = threadIdx.x;
    const int sub  = tid >> 5;              // 0..7
    const int pidx = tid & 31;              // 0..31
    const int q    = blockIdx.x * 32 + pidx;

    if (blockIdx.x == 0 && tid == 64) out[0] = 0.f;   // zero loss accumulator

    float s = 0.f;
    const int b0 = sub * 32;
    #pragma unroll 8
    for (int i = 0; i < 32; ++i)
        s += partials[(size_t)(b0 + i) * (C * D) + q];   // 128B coalesced
    red[sub][pidx] = s;
    __syncthreads();

    if (tid < 32) {
        float tot = 0.f;
        #pragma unroll
        for (int u = 0; u < 8; ++u) tot += red[u][tid];
        const int qq = blockIdx.x * 32 + tid;
        const int c = (qq >> 5) & 63;                    // layout: [kq][c][j]
        const int k = (qq >> 11) * 32 + (qq & 31);
        float cnt = cntSum[c];
        if (cnt < 0.5f) cnt = 1.f;          // class_counts + (counts < 0.01)
        tot /= cnt;
        pTg[((k >> 2) * 64 + (c & 3) * 16 + (c >> 2)) * 4 + (k & 3)] = tot;
    }
}

// ---- K3: 4x4-register-tile distances + logsumexp + atomic loss ------------
__global__ __launch_bounds__(256, 2) void k3_dist_loss(
    const float* __restrict__ x, const int* __restrict__ y,
    const float4* __restrict__ pTg4,    // [32][64] float4, finalized
    float* __restrict__ out)
{
    __shared__ float4 xrows4[K3_ROWS * LDX4];  // 33.8 KB, [row][k4] padded
    __shared__ float4 pT4[32 * 64];            // 32 KB, [k4][cc][cg]
    __shared__ float  wsum[4];
    const int tid = threadIdx.x;

    for (int o = tid; o < 32 * 64; o += 256) pT4[o] = pTg4[o];  // identity stage
    const int row0 = M_HALF + blockIdx.x * K3_ROWS;
    {
        const float4* src = (const float4*)(x + (size_t)row0 * D);
        for (int i = tid; i < K3_ROWS * (D / 4); i += 256)
            xrows4[(i >> 5) * LDX4 + (i & 31)] = src[i];
    }
    __syncthreads();

    const int lane = tid & 63;
    const int wid  = tid >> 6;
    const int cg   = lane & 15;      // classes 4*cg + cc
    const int rg   = lane >> 4;      // row group within wave
    const int rbase = wid * 16 + rg * 4;   // wave: 16 rows; thread: 4 rows

    float acc[4][4];
    #pragma unroll
    for (int r = 0; r < 4; ++r)
        #pragma unroll
        for (int cc = 0; cc < 4; ++cc) acc[r][cc] = 0.f;

    #pragma unroll 2
    for (int k4 = 0; k4 < 32; ++k4) {
        float4 pv[4], xv[4];
        #pragma unroll
        for (int cc = 0; cc < 4; ++cc) pv[cc] = pT4[k4 * 64 + cc * 16 + cg];
        #pragma unroll
        for (int r = 0; r < 4; ++r) xv[r] = xrows4[(rbase + r) * LDX4 + k4];
        #pragma unroll
        for (int r = 0; r < 4; ++r) {
            #pragma unroll
            for (int cc = 0; cc < 4; ++cc) {
                float d;
                d = xv[r].x - pv[cc].x; acc[r][cc] = fmaf(d, fabsf(d), acc[r][cc]);
                d = xv[r].y - pv[cc].y; acc[r][cc] = fmaf(d, fabsf(d), acc[r][cc]);
                d = xv[r].z - pv[cc].z; acc[r][cc] = fmaf(d, fabsf(d), acc[r][cc]);
                d = xv[r].w - pv[cc].w; acc[r][cc] = fmaf(d, fabsf(d), acc[r][cc]);
            }
        }
    }

    const float ninv_d = -1.f / (float)D;
    float lsum = 0.f;
    #pragma unroll
    for (int r = 0; r < 4; ++r) {
        float dv0 = acc[r][0] * ninv_d, dv1 = acc[r][1] * ninv_d;
        float dv2 = acc[r][2] * ninv_d, dv3 = acc[r][3] * ninv_d;
        float mx = fmaxf(fmaxf(dv0, dv1), fmaxf(dv2, dv3));
        #pragma unroll
        for (int off = 8; off; off >>= 1) mx = fmaxf(mx, __shfl_xor(mx, off));
        float se = __expf(dv0 - mx) + __expf(dv1 - mx) +
                   __expf(dv2 - mx) + __expf(dv3 - mx);
        #pragma unroll
        for (int off = 8; off; off >>= 1) se += __shfl_xor(se, off);
        const float lse = mx + __logf(se);

        const int yt  = y[row0 + rbase + r];     // uniform within 16-lane group
        const int cct = yt & 3, cgt = yt >> 2;   // class c = 4*cg + cc
        const float v01 = (cct & 1) ? dv1 : dv0;
        const float v23 = (cct & 1) ? dv3 : dv2;
        const float val = (cct & 2) ? v23 : v01;
        const float dy  = __shfl(val, (lane & 48) | cgt);
        lsum += lse - dy;                        // -logp[y]
    }

    lsum += __shfl_xor(lsum, 16);                // sum 4 rg-groups
    lsum += __shfl_xor(lsum, 32);

    if (lane == 0) wsum[wid] = lsum;
    __syncthreads();
    if (tid == 0) {
        const float tot = (wsum[0] + wsum[1] + wsum[2] + wsum[3]) * (1.f / (float)M_HALF);
        atomicAdd(out, tot);
    }
}

extern "C" void kernel_launch(void* const* d_in, const int* in_sizes, int n_in,
                              void* d_out, int out_size, void* d_ws, size_t ws_size,
                              hipStream_t stream) {
    const float* x = (const float*)d_in[0];   // [32768][128]
    const int*   y = (const int*)d_in[1];     // [32768]
    float* out = (float*)d_out;

    float* ws_f     = (float*)d_ws;
    float* cntSum   = ws_f;                              // 64 floats
    float* pTg      = cntSum + C;                        // 8192 floats
    float* partials = pTg + D * C;                       // 256*8192 = 8 MB

    hipMemsetAsync(cntSum, 0, C * sizeof(float), stream);
    k1_partials<<<K1_BLOCKS, 256, 0, stream>>>(x, y, partials, cntSum);
    k2_finalize<<<K2_BLOCKS, 256, 0, stream>>>(partials, cntSum, pTg, out);
    k3_dist_loss<<<K3_BLOCKS, 256, 0, stream>>>(x, y, (const float4*)pTg, out);
}

// Round 11
// 37.875 us; speedup vs baseline: 1.2596x; 1.1510x over previous
//
#include <hip/hip_runtime.h>

#define M_HALF 16384
#define D 128
#define C 64

#define K1_BLOCKS 256
#define K1_ROWS 64

#define K2_BLOCKS 256

#define K3_BLOCKS 256
#define K3_ROWS 64

// ---- K1: ballot + direct-global gather; zero LDS; coalesced partials ------
__global__ __launch_bounds__(256) void k1_partials(
    const float* __restrict__ x, const int* __restrict__ y,
    float* __restrict__ partials)   // [K1_BLOCKS][4][C][32]  (kq, c, j)
{
    const int tid  = threadIdx.x;
    const int lane = tid & 63;
    const int kq   = tid >> 6;               // wave id = k-quarter
    const int base = blockIdx.x * K1_ROWS;

    // per-wave: 64-bit row mask for class == lane
    const int ycl = y[base + lane];          // class of row 'lane'
    unsigned long long mymask = 0ULL;
    for (int ci = 0; ci < C; ++ci) {
        const unsigned long long m = __ballot(ycl == ci);
        if (lane == ci) mymask = m;
    }

    // gather-accumulate from global: class=lane, k in [kq*32, kq*32+32)
    float acc[32];
    #pragma unroll
    for (int j = 0; j < 32; ++j) acc[j] = 0.f;
    unsigned long long m = mymask;
    while (m) {
        const int r = (int)__builtin_ctzll(m);
        m &= m - 1;
        const float4* xr = (const float4*)(x + (size_t)(base + r) * D + kq * 32);
        #pragma unroll
        for (int j4 = 0; j4 < 8; ++j4) {
            const float4 v = xr[j4];
            acc[j4*4+0] += v.x; acc[j4*4+1] += v.y;
            acc[j4*4+2] += v.z; acc[j4*4+3] += v.w;
        }
    }

    // coalesced store: per-lane 128B contiguous, per-wave 8KB contiguous
    float* outp = partials + (size_t)blockIdx.x * (C * D) + (kq * 64 + lane) * 32;
    #pragma unroll
    for (int j4 = 0; j4 < 8; ++j4)
        *(float4*)&outp[j4 * 4] =
            make_float4(acc[j4*4], acc[j4*4+1], acc[j4*4+2], acc[j4*4+3]);
}

// ---- K2: self-counted partial reduction -> finalized pT table -------------
// Each block owns ONE class (c = blk & 63) and one k-quarter (kq = blk >> 6):
// counts its class from y directly (no atomics, no memset), reduces 256
// partials for its 32 slots, writes finalized pTg. Block 0 zeros out[0].
__global__ __launch_bounds__(256) void k2_finalize(
    const float* __restrict__ partials, const int* __restrict__ y,
    float* __restrict__ pTg,    // float idx: (k4*64 + cc*16 + cg)*4 + j
    float* __restrict__ out)
{
    __shared__ float red[8][33];
    __shared__ int   cred[4];
    const int tid = threadIdx.x;
    const int blk = blockIdx.x;
    const int myc = blk & 63;               // this block's class

    // count occurrences of myc in y[0:M_HALF]: int4 scan + wave reduce
    int cnt = 0;
    const int4* y4 = (const int4*)y;
    #pragma unroll 4
    for (int i = tid; i < M_HALF / 4; i += 256) {
        const int4 v = y4[i];
        cnt += (v.x == myc) + (v.y == myc) + (v.z == myc) + (v.w == myc);
    }
    #pragma unroll
    for (int off = 32; off; off >>= 1) cnt += __shfl_xor(cnt, off);
    if ((tid & 63) == 0) cred[tid >> 6] = cnt;

    if (blk == 0 && tid == 65) out[0] = 0.f;   // zero loss accumulator

    // partial reduction: 32 slots, 8 threads/slot over 32 K1-blocks each
    const int sub  = tid >> 5;              // 0..7
    const int pidx = tid & 31;              // 0..31
    const int q    = blk * 32 + pidx;       // flat [kq][c][j]
    float s = 0.f;
    const int b0 = sub * 32;
    #pragma unroll 8
    for (int i = 0; i < 32; ++i)
        s += partials[(size_t)(b0 + i) * (C * D) + q];   // 128B coalesced
    red[sub][pidx] = s;
    __syncthreads();

    if (tid < 32) {
        float tot = 0.f;
        #pragma unroll
        for (int u = 0; u < 8; ++u) tot += red[u][tid];
        float c = (float)(cred[0] + cred[1] + cred[2] + cred[3]);
        if (c < 0.5f) c = 1.f;              // class_counts + (counts < 0.01)
        tot /= c;
        const int k = (blk >> 6) * 32 + tid;          // kq*32 + j
        pTg[((k >> 2) * 64 + (myc & 3) * 16 + (myc >> 2)) * 4 + (k & 3)] = tot;
    }
}

// ---- K3: 4x4-register-tile distances; x direct from global (L2/L3) --------
__global__ __launch_bounds__(256) void k3_dist_loss(
    const float* __restrict__ x, const int* __restrict__ y,
    const float4* __restrict__ pTg4,    // [32][64] float4, finalized
    float* __restrict__ out)
{
    __shared__ float4 pT4[32 * 64];            // 32 KB, [k4][cc][cg]
    __shared__ float  wsum[4];
    const int tid = threadIdx.x;

    for (int o = tid; o < 32 * 64; o += 256) pT4[o] = pTg4[o];
    __syncthreads();

    const int lane = tid & 63;
    const int wid  = tid >> 6;
    const int cg   = lane & 15;      // classes 4*cg + cc
    const int rg   = lane >> 4;      // row group within wave
    const int rbase = wid * 16 + rg * 4;   // wave: 16 rows; thread: 4 rows
    const int row0 = M_HALF + blockIdx.x * K3_ROWS;

    const float4* xrow[4];
    #pragma unroll
    for (int r = 0; r < 4; ++r)
        xrow[r] = (const float4*)(x + (size_t)(row0 + rbase + r) * D);

    float acc[4][4];
    #pragma unroll
    for (int r = 0; r < 4; ++r)
        #pragma unroll
        for (int cc = 0; cc < 4; ++cc) acc[r][cc] = 0.f;

    #pragma unroll 2
    for (int k4 = 0; k4 < 32; ++k4) {
        float4 pv[4], xv[4];
        #pragma unroll
        for (int cc = 0; cc < 4; ++cc) pv[cc] = pT4[k4 * 64 + cc * 16 + cg];
        #pragma unroll
        for (int r = 0; r < 4; ++r) xv[r] = xrow[r][k4];   // 16-lane broadcast
        #pragma unroll
        for (int r = 0; r < 4; ++r) {
            #pragma unroll
            for (int cc = 0; cc < 4; ++cc) {
                float d;
                d = xv[r].x - pv[cc].x; acc[r][cc] = fmaf(d, fabsf(d), acc[r][cc]);
                d = xv[r].y - pv[cc].y; acc[r][cc] = fmaf(d, fabsf(d), acc[r][cc]);
                d = xv[r].z - pv[cc].z; acc[r][cc] = fmaf(d, fabsf(d), acc[r][cc]);
                d = xv[r].w - pv[cc].w; acc[r][cc] = fmaf(d, fabsf(d), acc[r][cc]);
            }
        }
    }

    const float ninv_d = -1.f / (float)D;
    float lsum = 0.f;
    #pragma unroll
    for (int r = 0; r < 4; ++r) {
        float dv0 = acc[r][0] * ninv_d, dv1 = acc[r][1] * ninv_d;
        float dv2 = acc[r][2] * ninv_d, dv3 = acc[r][3] * ninv_d;
        float mx = fmaxf(fmaxf(dv0, dv1), fmaxf(dv2, dv3));
        #pragma unroll
        for (int off = 8; off; off >>= 1) mx = fmaxf(mx, __shfl_xor(mx, off));
        float se = __expf(dv0 - mx) + __expf(dv1 - mx) +
                   __expf(dv2 - mx) + __expf(dv3 - mx);
        #pragma unroll
        for (int off = 8; off; off >>= 1) se += __shfl_xor(se, off);
        const float lse = mx + __logf(se);

        const int yt  = y[row0 + rbase + r];     // uniform within 16-lane group
        const int cct = yt & 3, cgt = yt >> 2;   // class c = 4*cg + cc
        const float v01 = (cct & 1) ? dv1 : dv0;
        const float v23 = (cct & 1) ? dv3 : dv2;
        const float val = (cct & 2) ? v23 : v01;
        const float dy  = __shfl(val, (lane & 48) | cgt);
        lsum += lse - dy;                        // -logp[y]
    }

    lsum += __shfl_xor(lsum, 16);                // sum 4 rg-groups
    lsum += __shfl_xor(lsum, 32);

    if (lane == 0) wsum[wid] = lsum;
    __syncthreads();
    if (tid == 0) {
        const float tot = (wsum[0] + wsum[1] + wsum[2] + wsum[3]) * (1.f / (float)M_HALF);
        atomicAdd(out, tot);
    }
}

extern "C" void kernel_launch(void* const* d_in, const int* in_sizes, int n_in,
                              void* d_out, int out_size, void* d_ws, size_t ws_size,
                              hipStream_t stream) {
    const float* x = (const float*)d_in[0];   // [32768][128]
    const int*   y = (const int*)d_in[1];     // [32768]
    float* out = (float*)d_out;

    float* ws_f     = (float*)d_ws;
    float* pTg      = ws_f;                              // 8192 floats
    float* partials = pTg + D * C;                       // 256*8192 = 8 MB

    k1_partials<<<K1_BLOCKS, 256, 0, stream>>>(x, y, partials);
    k2_finalize<<<K2_BLOCKS, 256, 0, stream>>>(partials, y, pTg, out);
    k3_dist_loss<<<K3_BLOCKS, 256, 0, stream>>>(x, y, (const float4*)pTg, out);
}